// Round 19
// baseline (151.114 us; speedup 1.0000x reference)
//
#include <hip/hip_runtime.h>
#include <math.h>

#define BATCH 8
#define SEQ   1024
#define DM    512
#define NH    8
#define DK    64

typedef short s8v __attribute__((ext_vector_type(8)));
typedef float f4v __attribute__((ext_vector_type(4)));

// workspace byte offsets
#define MB (1u<<20)
#define PE_OFF   0u
#define XBF_OFF  (1*MB)
#define WT_OFF   (25*MB)
#define WO_OFF   (27*MB)
#define QH_OFF   (28*MB)
#define KH_OFF   (36*MB)
#define VT_OFF   (44*MB)
#define PHR_OFF  (52*MB)
#define OB_OFF   (53*MB)

#define CF4(p) (*(const float4*)(p))
#define F4(p)  (*(float4*)(p))

__device__ __forceinline__ float bf2f(ushort u) {
    union { unsigned int i; float f; } x; x.i = ((unsigned int)u) << 16; return x.f;
}
__device__ __forceinline__ ushort f2bf(float f) {
    union { float f; unsigned int i; } x; x.f = f;
    unsigned int r = (x.i + 0x7FFFu + ((x.i >> 16) & 1u)) >> 16;
    return (ushort)r;
}
__device__ __forceinline__ void gload16(const void* g, void* l) {
    __builtin_amdgcn_global_load_lds(
        (const __attribute__((address_space(1))) unsigned int*)g,
        (__attribute__((address_space(3))) unsigned int*)l, 16, 0, 0);
}

// ---------------------------------------------------------------------------
__global__ void pe_make(ushort* __restrict__ pe) {
    const int r = blockIdx.x;
    const int i = threadIdx.x;
    float inv = __expf(-(float)i * (9.210340372f / 256.0f));
    float th = (float)r * inv;
    float s, c;
    __sincosf(th, &s, &c);
    pe[r * DM + 2 * i]     = f2bf(s);
    pe[r * DM + 2 * i + 1] = f2bf(c);
}

__global__ __launch_bounds__(256) void cvt_qkv(
    const float* __restrict__ q, const float* __restrict__ k,
    const float* __restrict__ v, ushort* __restrict__ xbf)
{
    const float* src = (blockIdx.y == 0) ? q : (blockIdx.y == 1) ? k : v;
    size_t idx = ((size_t)blockIdx.x * 256 + threadIdx.x) * 4;
    float4 f = CF4(&src[idx]);
    ushort4 u;
    u.x = f2bf(f.x); u.y = f2bf(f.y); u.z = f2bf(f.z); u.w = f2bf(f.w);
    *(ushort4*)&xbf[(size_t)blockIdx.y * 8192 * 512 + idx] = u;
}

__global__ __launch_bounds__(256) void cvt_wt(
    const float* __restrict__ wq, const float* __restrict__ wk,
    const float* __restrict__ wv, const float* __restrict__ wp,
    ushort* __restrict__ wt)
{
    const int z = blockIdx.z;
    const float* W = (z == 0) ? wq : (z == 1) ? wk : (z == 2) ? wv : wp;
    const int d0 = blockIdx.x * 64, h = blockIdx.y;
    __shared__ float t[64][65];
    const int tid = threadIdx.x;
    const int c = tid & 63, r0 = tid >> 6;
    #pragma unroll
    for (int it = 0; it < 16; ++it) {
        int r = r0 + it * 4;
        t[r][c] = W[(size_t)h * 32768 + (size_t)(d0 + r) * 64 + c];
    }
    __syncthreads();
    #pragma unroll
    for (int it = 0; it < 16; ++it) {
        int cc = r0 + it * 4;
        wt[(size_t)z * 262144 + ((size_t)h * 64 + cc) * 512 + d0 + (tid & 63)] =
            f2bf(t[tid & 63][cc]);
    }
}

__global__ __launch_bounds__(256) void cvt_wo(
    const float* __restrict__ wo, ushort* __restrict__ wobf)
{
    size_t idx = ((size_t)blockIdx.x * 256 + threadIdx.x) * 4;
    float4 f = CF4(&wo[idx]);
    ushort4 u;
    u.x = f2bf(f.x); u.y = f2bf(f.y); u.z = f2bf(f.z); u.w = f2bf(f.w);
    *(ushort4*)&wobf[idx] = u;
}

// ---------------------------------------------------------------------------
// MFMA GEMM (m97 structure, 128x128 tile, BK=64)
// ---------------------------------------------------------------------------
template<int MODE>
__global__ __launch_bounds__(256) void mfma_gemm(
    const ushort* __restrict__ xbf, const ushort* __restrict__ pebf,
    const ushort* __restrict__ wt,
    ushort* __restrict__ qh, ushort* __restrict__ kh, ushort* __restrict__ vt,
    ushort* __restrict__ phr,
    const ushort* __restrict__ Aob, const ushort* __restrict__ wobf,
    float* __restrict__ outf)
{
    const int z = (MODE == 0) ? blockIdx.z : 4;
    const ushort* A;
    const ushort* Bt;
    int M;
    if (MODE == 0) {
        A  = (z < 3) ? xbf + (size_t)z * 8192 * 512 : pebf;
        Bt = wt + (size_t)z * 262144;
        M  = (z < 3) ? 8192 : 1024;
    } else {
        A = Aob; Bt = wobf; M = 8192;
    }
    const int m0 = blockIdx.x * 128;
    if (m0 >= M) return;
    const int n0 = blockIdx.y * 128;

    __shared__ ushort lds[2][16384];

    const int tid = threadIdx.x;
    const int wave = tid >> 6, lane = tid & 63;
    const int lg = lane >> 4, ll = lane & 15;
    const int wr = wave >> 1, wc = wave & 1;

    f4v acc[4][4];
    #pragma unroll
    for (int i = 0; i < 4; ++i)
        #pragma unroll
        for (int j = 0; j < 4; ++j) { acc[i][j][0]=0; acc[i][j][1]=0; acc[i][j][2]=0; acc[i][j][3]=0; }

    auto stage = [&](int buf, int k0) {
        #pragma unroll
        for (int i = 0; i < 4; ++i) {
            int o = wave * 4096 + i * 1024 + lane * 16;
            int row = o >> 7, colb = o & 127;
            const char* ga = (const char*)A  + (size_t)(m0 + row) * 1024 + (size_t)k0 * 2 + colb;
            const char* gb = (const char*)Bt + (size_t)(n0 + row) * 1024 + (size_t)k0 * 2 + colb;
            char* la = (char*)&lds[buf][0] + wave * 4096 + i * 1024;
            char* lb = (char*)&lds[buf][0] + 16384 + wave * 4096 + i * 1024;
            gload16(ga, la);
            gload16(gb, lb);
        }
    };

    stage(0, 0);
    asm volatile("s_waitcnt vmcnt(0)" ::: "memory");
    __syncthreads();

    int cur = 0;
    for (int kt = 0; kt < 8; ++kt) {
        if (kt < 7) stage(cur ^ 1, (kt + 1) * 64);

        const ushort* a_ = &lds[cur][0];
        const ushort* b_ = &lds[cur][8192];
        s8v af[4][2], bf[4][2];
        #pragma unroll
        for (int i = 0; i < 4; ++i)
            #pragma unroll
            for (int c = 0; c < 2; ++c) {
                af[i][c] = *(const s8v*)(a_ + (wr * 64 + i * 16 + ll) * 64 + c * 32 + lg * 8);
                bf[i][c] = *(const s8v*)(b_ + (wc * 64 + i * 16 + ll) * 64 + c * 32 + lg * 8);
            }
        #pragma unroll
        for (int c = 0; c < 2; ++c)
            #pragma unroll
            for (int i = 0; i < 4; ++i)
                #pragma unroll
                for (int j = 0; j < 4; ++j)
                    acc[i][j] = __builtin_amdgcn_mfma_f32_16x16x32_bf16(af[i][c], bf[j][c], acc[i][j], 0, 0, 0);

        asm volatile("s_waitcnt vmcnt(0)" ::: "memory");
        __syncthreads();
        cur ^= 1;
    }

    #pragma unroll
    for (int i = 0; i < 4; ++i)
        #pragma unroll
        for (int j = 0; j < 4; ++j)
            #pragma unroll
            for (int q = 0; q < 4; ++q) {
                int m = m0 + wr * 64 + i * 16 + lg * 4 + q;
                int n = n0 + wc * 64 + j * 16 + ll;
                if (MODE == 0) {
                    ushort val = f2bf(acc[i][j][q]);
                    int b = m >> 10, s = m & 1023, hh = n >> 6, kk = n & 63;
                    if (z == 0) {
                        qh[((((size_t)b * NH + hh) << 10) + s) * 64 + kk] = val;
                    } else if (z == 1) {
                        kh[((((size_t)b * NH + hh) << 10) + s) * 64 + kk] = val;
                    } else if (z == 2) {
                        vt[((((size_t)b * NH + hh) * 64 + kk) << 10) + s] = val;
                    } else {
                        phr[((((size_t)hh) << 10) + m) * 64 + kk] = val;
                    }
                } else {
                    outf[(size_t)m * 512 + n] = acc[i][j][q];
                }
            }
}

// ---------------------------------------------------------------------------
// MFMA flash attention — 16-wave blocks (256 q-rows), per-wave code identical
// to the verified r9/r16 structure. K/V staged by half the threads each
// (1 uint4/thread/iter); PR window 320 rows shared by all 16 waves.
// Grid = 256 blocks = exactly 1 block/CU, 16 waves/CU.
// ---------------------------------------------------------------------------
__global__ __launch_bounds__(1024, 2) void attn_mfma(
    const ushort* __restrict__ qh, const ushort* __restrict__ kh,
    const ushort* __restrict__ vt, const ushort* __restrict__ phr,
    const float* __restrict__ bu, const float* __restrict__ bv,
    ushort* __restrict__ Ob)
{
    // XCD swizzle over 256 blocks (32 consecutive per XCD)
    const int L = blockIdx.x;
    const int wid = (L & 7) * 32 + (L >> 3);
    const int s0 = (wid & 3) * 256;
    const int bh = wid >> 2;
    const int b = bh >> 3, h = bh & 7;

    const int tid = threadIdx.x;          // 0..1023
    const int wave = tid >> 6, lane = tid & 63;
    const int lg = lane >> 4, ll = lane & 15;

    __shared__ ushort Ks[64 * 68];        // K tile, 136B rows
    __shared__ ushort Vts[64 * 68];       // V^T tile
    __shared__ ushort PRs[320 * 68];      // shared phr window (320 rows)
    __shared__ ushort BDP[16][80 * 18];   // per-wave bd scratch bf16
    ushort* bdw = BDP[wave];
    ushort* Pl  = bdw;                    // P overlay (two-pass safe)

    // wave-level diagonal base: band rows [s0+16w, s0+16w+16)
    const int sW = s0 + ((wave >> 2) << 6);

    s8v qu[2], qv[2];
    {
        const int row = s0 + wave * 16 + ll;
        const ushort* qrow = qh + (((size_t)b * NH + h) * SEQ + row) * DK;
        #pragma unroll
        for (int c = 0; c < 2; ++c) {
            int k0 = c * 32 + lg * 8;
            #pragma unroll
            for (int i = 0; i < 8; ++i) {
                float f = bf2f(qrow[k0 + i]);
                qu[c][i] = (short)f2bf((f + bu[h * DK + k0 + i]) * 0.125f);
                qv[c][i] = (short)f2bf((f + bv[h * DK + k0 + i]) * 0.125f);
            }
        }
    }

    f4v oacc[4];
    #pragma unroll
    for (int nb = 0; nb < 4; ++nb) { oacc[nb][0]=0; oacc[nb][1]=0; oacc[nb][2]=0; oacc[nb][3]=0; }
    float psum = 0.0f;

    const ushort* kbase = kh + ((size_t)b * NH + h) * SEQ * DK;
    const ushort* vtb   = vt + ((size_t)b * NH + h) * DK * SEQ;
    const ushort* pbase = phr + (size_t)h * SEQ * DK;

    // K/V staging split: threads 0..511 stage K, 512..1023 stage V
    const int sr = (tid & 511) >> 3, sc = ((tid & 511) & 7) * 8;
    const bool doK = (tid < 512);

    // ---- prologue: pre-issue staging loads for t0 = 0 ----
    uint4 kvreg, preg[3];
    kvreg = doK ? *(const uint4*)(kbase + (size_t)sr * DK + sc)
                : *(const uint4*)(vtb + (size_t)sr * SEQ + sc);
    #pragma unroll
    for (int it = 0; it < 3; ++it) {
        int f = tid + it * 1024;
        int r = f >> 3, c = (f & 7) * 8;
        int rg = s0 - 63 + r;
        preg[it] = (f < 2560 && (unsigned)rg < 1024u)
                   ? *(const uint4*)(pbase + (size_t)rg * DK + c)
                   : make_uint4(0, 0, 0, 0);
    }

    for (int t0 = 0; t0 < SEQ; t0 += 64) {
        const bool need_pr = (t0 <= s0 + 192);  // any wave needs bd
        const bool need_bd = (t0 <= sW);        // this wave computes bd

        // ---- write staged regs to LDS ----
        if (doK) *(uint4*)((char*)Ks  + sr * 136 + sc * 2) = kvreg;
        else     *(uint4*)((char*)Vts + sr * 136 + sc * 2) = kvreg;
        if (need_pr) {
            #pragma unroll
            for (int it = 0; it < 3; ++it) {
                int f = tid + it * 1024;
                if (f < 2560) {
                    int r = f >> 3, c = (f & 7) * 8;
                    *(uint4*)((char*)PRs + r * 136 + c * 2) = preg[it];
                }
            }
        }
        __syncthreads();

        // ---- pre-issue next tile's loads (hidden under compute) ----
        if (t0 < SEQ - 64) {
            kvreg = doK ? *(const uint4*)(kbase + (size_t)(t0 + 64 + sr) * DK + sc)
                        : *(const uint4*)(vtb + (size_t)sr * SEQ + t0 + 64 + sc);
            if (t0 <= s0 + 128) {   // next tile needs PR
                int rbase_n = s0 - t0 - 127;
                #pragma unroll
                for (int it = 0; it < 3; ++it) {
                    int f = tid + it * 1024;
                    int rr = f >> 3, cc = (f & 7) * 8;
                    int rg = rbase_n + rr;
                    preg[it] = (f < 2560 && (unsigned)rg < 1024u)
                               ? *(const uint4*)(pbase + (size_t)rg * DK + cc)
                               : make_uint4(0, 0, 0, 0);
                }
            }
        }

        // ---- S^T = K . Qu^T ----
        f4v sacc[4];
        #pragma unroll
        for (int nb = 0; nb < 4; ++nb) { sacc[nb][0]=0; sacc[nb][1]=0; sacc[nb][2]=0; sacc[nb][3]=0; }
        #pragma unroll
        for (int nb = 0; nb < 4; ++nb) {
            #pragma unroll
            for (int c = 0; c < 2; ++c) {
                s8v kf = *(const s8v*)((const char*)Ks + (nb * 16 + ll) * 136 + c * 64 + lg * 16);
                sacc[nb] = __builtin_amdgcn_mfma_f32_16x16x32_bf16(kf, qu[c], sacc[nb], 0, 0, 0);
            }
        }
        // ---- BD^T = PR . Qv^T (wave band at window offset wave*16) ----
        if (need_bd) {
            #pragma unroll
            for (int pbl = 0; pbl < 5; ++pbl) {
                int lrow = wave * 16 + pbl * 16 + ll;     // 0..319
                f4v bdacc; bdacc[0]=0; bdacc[1]=0; bdacc[2]=0; bdacc[3]=0;
                #pragma unroll
                for (int c = 0; c < 2; ++c) {
                    s8v pf = *(const s8v*)((const char*)PRs + lrow * 136 + c * 64 + lg * 16);
                    bdacc = __builtin_amdgcn_mfma_f32_16x16x32_bf16(pf, qv[c], bdacc, 0, 0, 0);
                }
                #pragma unroll
                for (int qq = 0; qq < 4; ++qq)
                    bdw[(pbl * 16 + lg * 4 + qq) * 18 + ll] = f2bf(bdacc[qq]);
            }
        }

        // ---- pass 1: add bd into sacc in place (reads only) ----
        if (need_bd) {
            #pragma unroll
            for (int nb = 0; nb < 4; ++nb)
                #pragma unroll
                for (int qq = 0; qq < 4; ++qq)
                    sacc[nb][qq] += bf2f(bdw[(ll + 63 - nb * 16 - lg * 4 - qq) * 18 + ll]);
        }

        // ---- pass 2: fixed-max exp, psum, write P ----
        #pragma unroll
        for (int nb = 0; nb < 4; ++nb) {
            float e0 = __expf(sacc[nb][0]);
            float e1 = __expf(sacc[nb][1]);
            float e2 = __expf(sacc[nb][2]);
            float e3 = __expf(sacc[nb][3]);
            psum += (e0 + e1) + (e2 + e3);
            ushort4 u;
            u.x = f2bf(e0); u.y = f2bf(e1); u.z = f2bf(e2); u.w = f2bf(e3);
            *(ushort4*)((char*)Pl + ll * 136 + nb * 32 + lg * 8) = u;
        }

        // ---- O^T += V^T . P ----
        s8v pb[2];
        #pragma unroll
        for (int c = 0; c < 2; ++c)
            pb[c] = *(const s8v*)((const char*)Pl + ll * 136 + c * 64 + lg * 16);
        #pragma unroll
        for (int nb = 0; nb < 4; ++nb) {
            #pragma unroll
            for (int c = 0; c < 2; ++c) {
                s8v vf = *(const s8v*)((const char*)Vts + (nb * 16 + ll) * 136 + c * 64 + lg * 16);
                oacc[nb] = __builtin_amdgcn_mfma_f32_16x16x32_bf16(vf, pb[c], oacc[nb], 0, 0, 0);
            }
        }
        __syncthreads();
    }

    psum += __shfl_xor(psum, 16);
    psum += __shfl_xor(psum, 32);
    float inv = 1.0f / psum;

    const int s = s0 + wave * 16 + ll;
    #pragma unroll
    for (int nb = 0; nb < 4; ++nb) {
        ushort4 u;
        u.x = f2bf(oacc[nb][0] * inv); u.y = f2bf(oacc[nb][1] * inv);
        u.z = f2bf(oacc[nb][2] * inv); u.w = f2bf(oacc[nb][3] * inv);
        *(ushort4*)&Ob[((((size_t)b) << 10) + s) * 512 + h * 64 + nb * 16 + lg * 4] = u;
    }
}

// ---------------------------------------------------------------------------
extern "C" void kernel_launch(void* const* d_in, const int* in_sizes, int n_in,
                              void* d_out, int out_size, void* d_ws, size_t ws_size,
                              hipStream_t stream)
{
    const float* q  = (const float*)d_in[0];
    const float* k  = (const float*)d_in[1];
    const float* v  = (const float*)d_in[2];
    const float* wq = (const float*)d_in[4];
    const float* wk = (const float*)d_in[5];
    const float* wv = (const float*)d_in[6];
    const float* wp = (const float*)d_in[7];
    const float* bu = (const float*)d_in[8];
    const float* bv = (const float*)d_in[9];
    const float* wo = (const float*)d_in[10];

    char* wsb = (char*)d_ws;
    ushort* pebf = (ushort*)(wsb + PE_OFF);
    ushort* xbf  = (ushort*)(wsb + XBF_OFF);
    ushort* wt   = (ushort*)(wsb + WT_OFF);
    ushort* wobf = (ushort*)(wsb + WO_OFF);
    ushort* qh   = (ushort*)(wsb + QH_OFF);
    ushort* kh   = (ushort*)(wsb + KH_OFF);
    ushort* vt   = (ushort*)(wsb + VT_OFF);
    ushort* phr  = (ushort*)(wsb + PHR_OFF);
    ushort* Ob   = (ushort*)(wsb + OB_OFF);

    pe_make<<<dim3(SEQ), dim3(256), 0, stream>>>(pebf);
    cvt_qkv<<<dim3(4096, 3), dim3(256), 0, stream>>>(q, k, v, xbf);
    cvt_wt<<<dim3(8, 8, 4), dim3(256), 0, stream>>>(wq, wk, wv, wp, wt);
    cvt_wo<<<dim3(256), dim3(256), 0, stream>>>(wo, wobf);

    mfma_gemm<0><<<dim3(64, 4, 4), dim3(256), 0, stream>>>(
        xbf, pebf, wt, qh, kh, vt, phr, nullptr, nullptr, nullptr);

    attn_mfma<<<dim3(256), dim3(1024), 0, stream>>>(
        qh, kh, vt, phr, bu, bv, Ob);

    mfma_gemm<1><<<dim3(64, 4), dim3(256), 0, stream>>>(
        nullptr, nullptr, nullptr, nullptr, nullptr, nullptr, nullptr,
        Ob, wobf, (float*)d_out);
}

// Round 20
// 140.610 us; speedup vs baseline: 1.0747x; 1.0747x over previous
//
#include <hip/hip_runtime.h>
#include <math.h>

#define BATCH 8
#define SEQ   1024
#define DM    512
#define NH    8
#define DK    64

typedef short s8v __attribute__((ext_vector_type(8)));
typedef float f4v __attribute__((ext_vector_type(4)));

// workspace byte offsets
#define MB (1u<<20)
#define PE_OFF   0u
#define XBF_OFF  (1*MB)
#define WT_OFF   (25*MB)
#define WO_OFF   (27*MB)
#define QH_OFF   (28*MB)
#define KH_OFF   (36*MB)
#define VT_OFF   (44*MB)
#define PHR_OFF  (52*MB)
#define OB_OFF   (53*MB)

#define CF4(p) (*(const float4*)(p))
#define F4(p)  (*(float4*)(p))

__device__ __forceinline__ float bf2f(ushort u) {
    union { unsigned int i; float f; } x; x.i = ((unsigned int)u) << 16; return x.f;
}
__device__ __forceinline__ ushort f2bf(float f) {
    union { float f; unsigned int i; } x; x.f = f;
    unsigned int r = (x.i + 0x7FFFu + ((x.i >> 16) & 1u)) >> 16;
    return (ushort)r;
}
__device__ __forceinline__ void gload16(const void* g, void* l) {
    __builtin_amdgcn_global_load_lds(
        (const __attribute__((address_space(1))) unsigned int*)g,
        (__attribute__((address_space(3))) unsigned int*)l, 16, 0, 0);
}

// ---------------------------------------------------------------------------
// Fused prep: block-range dispatch over the four independent conversion jobs.
//   [0, 12288)          cvt_qkv   (y = bid/4096, x = bid%4096)
//   [12288, 13312)      pe_make   (r = bid - 12288)
//   [13312, 13568)      cvt_wt    (z = i>>6, h = (i>>3)&7, d0 = (i&7)*64)
//   [13568, 13824)      cvt_wo
// ---------------------------------------------------------------------------
__global__ __launch_bounds__(256) void prep(
    const float* __restrict__ q, const float* __restrict__ k,
    const float* __restrict__ v,
    const float* __restrict__ wq, const float* __restrict__ wk,
    const float* __restrict__ wv, const float* __restrict__ wp,
    const float* __restrict__ wo,
    ushort* __restrict__ pe, ushort* __restrict__ xbf,
    ushort* __restrict__ wt, ushort* __restrict__ wobf)
{
    __shared__ float t[64][65];
    int bid = blockIdx.x;
    const int tid = threadIdx.x;

    if (bid < 12288) {                       // ---- cvt_qkv ----
        int y = bid / 4096, x = bid - y * 4096;
        const float* src = (y == 0) ? q : (y == 1) ? k : v;
        size_t idx = ((size_t)x * 256 + tid) * 4;
        float4 f = CF4(&src[idx]);
        ushort4 u;
        u.x = f2bf(f.x); u.y = f2bf(f.y); u.z = f2bf(f.z); u.w = f2bf(f.w);
        *(ushort4*)&xbf[(size_t)y * 8192 * 512 + idx] = u;
        return;
    }
    bid -= 12288;
    if (bid < 1024) {                        // ---- pe_make ----
        const int r = bid, i = tid;
        float inv = __expf(-(float)i * (9.210340372f / 256.0f));
        float th = (float)r * inv;
        float s, c;
        __sincosf(th, &s, &c);
        pe[r * DM + 2 * i]     = f2bf(s);
        pe[r * DM + 2 * i + 1] = f2bf(c);
        return;
    }
    bid -= 1024;
    if (bid < 256) {                         // ---- cvt_wt ----
        const int z = bid >> 6, h = (bid >> 3) & 7, d0 = (bid & 7) * 64;
        const float* W = (z == 0) ? wq : (z == 1) ? wk : (z == 2) ? wv : wp;
        const int c = tid & 63, r0 = tid >> 6;
        #pragma unroll
        for (int it = 0; it < 16; ++it) {
            int r = r0 + it * 4;
            t[r][c] = W[(size_t)h * 32768 + (size_t)(d0 + r) * 64 + c];
        }
        __syncthreads();
        #pragma unroll
        for (int it = 0; it < 16; ++it) {
            int cc = r0 + it * 4;
            wt[(size_t)z * 262144 + ((size_t)h * 64 + cc) * 512 + d0 + (tid & 63)] =
                f2bf(t[tid & 63][cc]);
        }
        return;
    }
    bid -= 256;
    {                                        // ---- cvt_wo ----
        size_t idx = ((size_t)bid * 256 + tid) * 4;
        float4 f = CF4(&wo[idx]);
        ushort4 u;
        u.x = f2bf(f.x); u.y = f2bf(f.y); u.z = f2bf(f.z); u.w = f2bf(f.w);
        *(ushort4*)&wobf[idx] = u;
    }
}

// ---------------------------------------------------------------------------
// MFMA GEMM (m97 structure, 128x128 tile, BK=64)
// ---------------------------------------------------------------------------
template<int MODE>
__global__ __launch_bounds__(256) void mfma_gemm(
    const ushort* __restrict__ xbf, const ushort* __restrict__ pebf,
    const ushort* __restrict__ wt,
    ushort* __restrict__ qh, ushort* __restrict__ kh, ushort* __restrict__ vt,
    ushort* __restrict__ phr,
    const ushort* __restrict__ Aob, const ushort* __restrict__ wobf,
    float* __restrict__ outf)
{
    const int z = (MODE == 0) ? blockIdx.z : 4;
    const ushort* A;
    const ushort* Bt;
    int M;
    if (MODE == 0) {
        A  = (z < 3) ? xbf + (size_t)z * 8192 * 512 : pebf;
        Bt = wt + (size_t)z * 262144;
        M  = (z < 3) ? 8192 : 1024;
    } else {
        A = Aob; Bt = wobf; M = 8192;
    }
    const int m0 = blockIdx.x * 128;
    if (m0 >= M) return;
    const int n0 = blockIdx.y * 128;

    __shared__ ushort lds[2][16384];

    const int tid = threadIdx.x;
    const int wave = tid >> 6, lane = tid & 63;
    const int lg = lane >> 4, ll = lane & 15;
    const int wr = wave >> 1, wc = wave & 1;

    f4v acc[4][4];
    #pragma unroll
    for (int i = 0; i < 4; ++i)
        #pragma unroll
        for (int j = 0; j < 4; ++j) { acc[i][j][0]=0; acc[i][j][1]=0; acc[i][j][2]=0; acc[i][j][3]=0; }

    auto stage = [&](int buf, int k0) {
        #pragma unroll
        for (int i = 0; i < 4; ++i) {
            int o = wave * 4096 + i * 1024 + lane * 16;
            int row = o >> 7, colb = o & 127;
            const char* ga = (const char*)A  + (size_t)(m0 + row) * 1024 + (size_t)k0 * 2 + colb;
            const char* gb = (const char*)Bt + (size_t)(n0 + row) * 1024 + (size_t)k0 * 2 + colb;
            char* la = (char*)&lds[buf][0] + wave * 4096 + i * 1024;
            char* lb = (char*)&lds[buf][0] + 16384 + wave * 4096 + i * 1024;
            gload16(ga, la);
            gload16(gb, lb);
        }
    };

    stage(0, 0);
    asm volatile("s_waitcnt vmcnt(0)" ::: "memory");
    __syncthreads();

    int cur = 0;
    for (int kt = 0; kt < 8; ++kt) {
        if (kt < 7) stage(cur ^ 1, (kt + 1) * 64);

        const ushort* a_ = &lds[cur][0];
        const ushort* b_ = &lds[cur][8192];
        s8v af[4][2], bf[4][2];
        #pragma unroll
        for (int i = 0; i < 4; ++i)
            #pragma unroll
            for (int c = 0; c < 2; ++c) {
                af[i][c] = *(const s8v*)(a_ + (wr * 64 + i * 16 + ll) * 64 + c * 32 + lg * 8);
                bf[i][c] = *(const s8v*)(b_ + (wc * 64 + i * 16 + ll) * 64 + c * 32 + lg * 8);
            }
        #pragma unroll
        for (int c = 0; c < 2; ++c)
            #pragma unroll
            for (int i = 0; i < 4; ++i)
                #pragma unroll
                for (int j = 0; j < 4; ++j)
                    acc[i][j] = __builtin_amdgcn_mfma_f32_16x16x32_bf16(af[i][c], bf[j][c], acc[i][j], 0, 0, 0);

        asm volatile("s_waitcnt vmcnt(0)" ::: "memory");
        __syncthreads();
        cur ^= 1;
    }

    #pragma unroll
    for (int i = 0; i < 4; ++i)
        #pragma unroll
        for (int j = 0; j < 4; ++j)
            #pragma unroll
            for (int q = 0; q < 4; ++q) {
                int m = m0 + wr * 64 + i * 16 + lg * 4 + q;
                int n = n0 + wc * 64 + j * 16 + ll;
                if (MODE == 0) {
                    ushort val = f2bf(acc[i][j][q]);
                    int b = m >> 10, s = m & 1023, hh = n >> 6, kk = n & 63;
                    if (z == 0) {
                        qh[((((size_t)b * NH + hh) << 10) + s) * 64 + kk] = val;
                    } else if (z == 1) {
                        kh[((((size_t)b * NH + hh) << 10) + s) * 64 + kk] = val;
                    } else if (z == 2) {
                        vt[((((size_t)b * NH + hh) * 64 + kk) << 10) + s] = val;
                    } else {
                        phr[((((size_t)hh) << 10) + m) * 64 + kk] = val;
                    }
                } else {
                    outf[(size_t)m * 512 + n] = acc[i][j][q];
                }
            }
}

// ---------------------------------------------------------------------------
// MFMA flash attention — 8-wave blocks (128 q-rows), verified optimum.
// K/V tiles shared by 2x compute; PR window 192 rows; 2 blk/CU x 8 waves.
// ---------------------------------------------------------------------------
__global__ __launch_bounds__(512, 4) void attn_mfma(
    const ushort* __restrict__ qh, const ushort* __restrict__ kh,
    const ushort* __restrict__ vt, const ushort* __restrict__ phr,
    const float* __restrict__ bu, const float* __restrict__ bv,
    ushort* __restrict__ Ob)
{
    // XCD swizzle over 512 blocks (64 consecutive per XCD)
    const int L = blockIdx.x;
    const int wid = (L & 7) * 64 + (L >> 3);
    const int s0 = (wid & 7) * 128;
    const int bh = wid >> 3;
    const int b = bh >> 3, h = bh & 7;

    const int tid = threadIdx.x;          // 0..511
    const int wave = tid >> 6, lane = tid & 63;
    const int lg = lane >> 4, ll = lane & 15;

    __shared__ ushort Ks[64 * 68];        // K tile, 136B rows
    __shared__ ushort Vts[64 * 68];       // V^T tile
    __shared__ ushort PRs[192 * 68];      // shared phr window (192 rows)
    __shared__ ushort BDP[8][80 * 18];    // per-wave bd scratch bf16
    ushort* bdw = BDP[wave];
    ushort* Pl  = bdw;                    // P overlay (two-pass safe)

    // wave-level diagonal base: rows [s0+16w, s0+16w+16)
    const int sW = s0 + ((wave >> 2) << 6);

    s8v qu[2], qv[2];
    {
        const int row = s0 + wave * 16 + ll;
        const ushort* qrow = qh + (((size_t)b * NH + h) * SEQ + row) * DK;
        #pragma unroll
        for (int c = 0; c < 2; ++c) {
            int k0 = c * 32 + lg * 8;
            #pragma unroll
            for (int i = 0; i < 8; ++i) {
                float f = bf2f(qrow[k0 + i]);
                qu[c][i] = (short)f2bf((f + bu[h * DK + k0 + i]) * 0.125f);
                qv[c][i] = (short)f2bf((f + bv[h * DK + k0 + i]) * 0.125f);
            }
        }
    }

    f4v oacc[4];
    #pragma unroll
    for (int nb = 0; nb < 4; ++nb) { oacc[nb][0]=0; oacc[nb][1]=0; oacc[nb][2]=0; oacc[nb][3]=0; }
    float psum = 0.0f;

    const ushort* kbase = kh + ((size_t)b * NH + h) * SEQ * DK;
    const ushort* vtb   = vt + ((size_t)b * NH + h) * DK * SEQ;
    const ushort* pbase = phr + (size_t)h * SEQ * DK;

    // ---- prologue: pre-issue staging loads for t0 = 0 ----
    uint4 kreg, vreg, preg[3];
    {
        int r = tid >> 3, c = (tid & 7) * 8;
        kreg = *(const uint4*)(kbase + (size_t)r * DK + c);
        vreg = *(const uint4*)(vtb + (size_t)r * SEQ + c);
    }
    #pragma unroll
    for (int it = 0; it < 3; ++it) {
        int f = tid + it * 512;
        int r = f >> 3, c = (f & 7) * 8;
        int rg = s0 - 63 + r;
        preg[it] = ((unsigned)rg < 1024u)
                   ? *(const uint4*)(pbase + (size_t)rg * DK + c)
                   : make_uint4(0, 0, 0, 0);
    }

    for (int t0 = 0; t0 < SEQ; t0 += 64) {
        const bool need_pr = (t0 <= s0 + 64);   // block-level staging
        const bool need_bd = (t0 <= sW);        // wave-level compute

        // ---- write staged regs to LDS ----
        {
            int r = tid >> 3, c = (tid & 7) * 8;
            *(uint4*)((char*)Ks  + r * 136 + c * 2) = kreg;
            *(uint4*)((char*)Vts + r * 136 + c * 2) = vreg;
        }
        if (need_pr) {
            #pragma unroll
            for (int it = 0; it < 3; ++it) {
                int f = tid + it * 512;
                int r = f >> 3, c = (f & 7) * 8;
                *(uint4*)((char*)PRs + r * 136 + c * 2) = preg[it];
            }
        }
        __syncthreads();

        // ---- pre-issue next tile's loads (hidden under compute) ----
        if (t0 < SEQ - 64) {
            int r = tid >> 3, c = (tid & 7) * 8;
            kreg = *(const uint4*)(kbase + (size_t)(t0 + 64 + r) * DK + c);
            vreg = *(const uint4*)(vtb + (size_t)r * SEQ + t0 + 64 + c);
            if (t0 <= s0) {   // next tile needs PR
                int rbase_n = s0 - t0 - 127;
                #pragma unroll
                for (int it = 0; it < 3; ++it) {
                    int f = tid + it * 512;
                    int rr = f >> 3, cc = (f & 7) * 8;
                    int rg = rbase_n + rr;
                    preg[it] = ((unsigned)rg < 1024u)
                               ? *(const uint4*)(pbase + (size_t)rg * DK + cc)
                               : make_uint4(0, 0, 0, 0);
                }
            }
        }

        // ---- S^T = K . Qu^T ----
        f4v sacc[4];
        #pragma unroll
        for (int nb = 0; nb < 4; ++nb) { sacc[nb][0]=0; sacc[nb][1]=0; sacc[nb][2]=0; sacc[nb][3]=0; }
        #pragma unroll
        for (int nb = 0; nb < 4; ++nb) {
            #pragma unroll
            for (int c = 0; c < 2; ++c) {
                s8v kf = *(const s8v*)((const char*)Ks + (nb * 16 + ll) * 136 + c * 64 + lg * 16);
                sacc[nb] = __builtin_amdgcn_mfma_f32_16x16x32_bf16(kf, qu[c], sacc[nb], 0, 0, 0);
            }
        }
        // ---- BD^T = PR . Qv^T (wave band at window offset wave*16) ----
        if (need_bd) {
            #pragma unroll
            for (int pbl = 0; pbl < 5; ++pbl) {
                int lrow = wave * 16 + pbl * 16 + ll;     // 0..191
                f4v bdacc; bdacc[0]=0; bdacc[1]=0; bdacc[2]=0; bdacc[3]=0;
                #pragma unroll
                for (int c = 0; c < 2; ++c) {
                    s8v pf = *(const s8v*)((const char*)PRs + lrow * 136 + c * 64 + lg * 16);
                    bdacc = __builtin_amdgcn_mfma_f32_16x16x32_bf16(pf, qv[c], bdacc, 0, 0, 0);
                }
                #pragma unroll
                for (int qq = 0; qq < 4; ++qq)
                    bdw[(pbl * 16 + lg * 4 + qq) * 18 + ll] = f2bf(bdacc[qq]);
            }
        }

        // ---- pass 1: add bd into sacc in place (reads only) ----
        if (need_bd) {
            #pragma unroll
            for (int nb = 0; nb < 4; ++nb)
                #pragma unroll
                for (int qq = 0; qq < 4; ++qq)
                    sacc[nb][qq] += bf2f(bdw[(ll + 63 - nb * 16 - lg * 4 - qq) * 18 + ll]);
        }

        // ---- pass 2: fixed-max exp, psum, write P ----
        #pragma unroll
        for (int nb = 0; nb < 4; ++nb) {
            float e0 = __expf(sacc[nb][0]);
            float e1 = __expf(sacc[nb][1]);
            float e2 = __expf(sacc[nb][2]);
            float e3 = __expf(sacc[nb][3]);
            psum += (e0 + e1) + (e2 + e3);
            ushort4 u;
            u.x = f2bf(e0); u.y = f2bf(e1); u.z = f2bf(e2); u.w = f2bf(e3);
            *(ushort4*)((char*)Pl + ll * 136 + nb * 32 + lg * 8) = u;
        }

        // ---- O^T += V^T . P ----
        s8v pb[2];
        #pragma unroll
        for (int c = 0; c < 2; ++c)
            pb[c] = *(const s8v*)((const char*)Pl + ll * 136 + c * 64 + lg * 16);
        #pragma unroll
        for (int nb = 0; nb < 4; ++nb) {
            #pragma unroll
            for (int c = 0; c < 2; ++c) {
                s8v vf = *(const s8v*)((const char*)Vts + (nb * 16 + ll) * 136 + c * 64 + lg * 16);
                oacc[nb] = __builtin_amdgcn_mfma_f32_16x16x32_bf16(vf, pb[c], oacc[nb], 0, 0, 0);
            }
        }
        __syncthreads();
    }

    psum += __shfl_xor(psum, 16);
    psum += __shfl_xor(psum, 32);
    float inv = 1.0f / psum;

    const int s = s0 + wave * 16 + ll;
    #pragma unroll
    for (int nb = 0; nb < 4; ++nb) {
        ushort4 u;
        u.x = f2bf(oacc[nb][0] * inv); u.y = f2bf(oacc[nb][1] * inv);
        u.z = f2bf(oacc[nb][2] * inv); u.w = f2bf(oacc[nb][3] * inv);
        *(ushort4*)&Ob[((((size_t)b) << 10) + s) * 512 + h * 64 + nb * 16 + lg * 4] = u;
    }
}

// ---------------------------------------------------------------------------
extern "C" void kernel_launch(void* const* d_in, const int* in_sizes, int n_in,
                              void* d_out, int out_size, void* d_ws, size_t ws_size,
                              hipStream_t stream)
{
    const float* q  = (const float*)d_in[0];
    const float* k  = (const float*)d_in[1];
    const float* v  = (const float*)d_in[2];
    const float* wq = (const float*)d_in[4];
    const float* wk = (const float*)d_in[5];
    const float* wv = (const float*)d_in[6];
    const float* wp = (const float*)d_in[7];
    const float* bu = (const float*)d_in[8];
    const float* bv = (const float*)d_in[9];
    const float* wo = (const float*)d_in[10];

    char* wsb = (char*)d_ws;
    ushort* pebf = (ushort*)(wsb + PE_OFF);
    ushort* xbf  = (ushort*)(wsb + XBF_OFF);
    ushort* wt   = (ushort*)(wsb + WT_OFF);
    ushort* wobf = (ushort*)(wsb + WO_OFF);
    ushort* qh   = (ushort*)(wsb + QH_OFF);
    ushort* kh   = (ushort*)(wsb + KH_OFF);
    ushort* vt   = (ushort*)(wsb + VT_OFF);
    ushort* phr  = (ushort*)(wsb + PHR_OFF);
    ushort* Ob   = (ushort*)(wsb + OB_OFF);

    prep<<<dim3(13824), dim3(256), 0, stream>>>(
        q, k, v, wq, wk, wv, wp, wo, pebf, xbf, wt, wobf);

    mfma_gemm<0><<<dim3(64, 4, 4), dim3(256), 0, stream>>>(
        xbf, pebf, wt, qh, kh, vt, phr, nullptr, nullptr, nullptr);

    attn_mfma<<<dim3(512), dim3(512), 0, stream>>>(
        qh, kh, vt, phr, bu, bv, Ob);

    mfma_gemm<1><<<dim3(64, 4), dim3(256), 0, stream>>>(
        nullptr, nullptr, nullptr, nullptr, nullptr, nullptr, nullptr,
        Ob, wobf, (float*)d_out);
}